// Round 1
// baseline (1688.790 us; speedup 1.0000x reference)
//
#include <hip/hip_runtime.h>
#include <math.h>

#define PNUM 300000
#define B_ 2
#define D0 144
#define H0 64
#define W0 160
#define C0 32

#define D1 72
#define H1 32
#define W1 80
#define C1 64
#define N1S (B_*D1*H1*W1)   // 368640

#define D2 36
#define H2 16
#define W2 40
#define C2R 96
#define N2S (B_*D2*H2*W2)   // 46080

#define D3 18
#define H3 8
#define W3 20
#define N3S (B_*D3*H3*W3)   // 5760

#define D4 9
#define H4 4
#define W4 10
#define N4S (B_*D4*H4*W4)   // 720

#define EPS_ 1e-4f
#define LEAK_ 0.2f

// workspace layout (float offsets)
#define OFF_CNT   0                       // 2,949,120
#define OFF_X1    2949120                 // 23,592,960
#define OFF_STATS 26542080                // 1024
#define OFF_M1    26543104                // 368,640
#define OFF_X2    26911744                // 5,898,240 (46080*128, couts 96..127 zero)
#define OFF_M2    32809984                // 46,080
#define OFF_X3    32856064                // 737,280
#define OFF_M3    33593344                // 5,760
// total 33,599,104 floats = 134.4 MB

// ---------------- densify count ----------------
__global__ __launch_bounds__(256) void k_count(const int* __restrict__ coords,
                                               float* __restrict__ cnt) {
  int i = blockIdx.x * 256 + threadIdx.x;
  if (i >= PNUM) return;
  int b = coords[i*4], x = coords[i*4+1], y = coords[i*4+2], z = coords[i*4+3];
  atomicAdd(&cnt[((b*D0 + x)*H0 + y)*W0 + z], 1.0f);
}

// ---------------- fused densify + conv1 (scatter) ----------------
// contribution of point i to parent site: (f_i / cnt) . w1[k]  (sum over dups = conv of mean)
__global__ __launch_bounds__(256) void k_scatter_conv1(
    const float* __restrict__ feat, const int* __restrict__ coords,
    const float* __restrict__ cnt, const float* __restrict__ w1,
    float* __restrict__ x1) {
  // LDS layout ws[ci][co4][k][4]: lane-divergent k -> bank offset 4 floats -> conflict-free b128
  __shared__ float ws[16384];   // 64 KB
  int t = threadIdx.x;
  for (int idx = t; idx < 16384; idx += 256) {
    int k = idx >> 11, ci = (idx >> 6) & 31, co = idx & 63;
    ws[ci*512 + (co >> 2)*32 + k*4 + (co & 3)] = w1[idx];
  }
  __syncthreads();
  int i = blockIdx.x * 256 + t;
  if (i >= PNUM) return;
  int b = coords[i*4], x = coords[i*4+1], y = coords[i*4+2], z = coords[i*4+3];
  int lin = ((b*D0 + x)*H0 + y)*W0 + z;
  float inv = 1.0f / cnt[lin];
  int k = ((x & 1) << 2) | ((y & 1) << 1) | (z & 1);
  int obase = (((b*D1 + (x >> 1))*H1 + (y >> 1))*W1 + (z >> 1)) * C1;
  float fr[32];
  const float4* fp = (const float4*)(feat + (size_t)i * 32);
#pragma unroll
  for (int q = 0; q < 8; q++) {
    float4 v = fp[q];
    fr[q*4+0] = v.x * inv; fr[q*4+1] = v.y * inv;
    fr[q*4+2] = v.z * inv; fr[q*4+3] = v.w * inv;
  }
#pragma unroll
  for (int c4 = 0; c4 < 16; c4++) {
    float4 acc = {0.f, 0.f, 0.f, 0.f};
    const float4* wp = (const float4*)(ws + c4*32 + k*4);
#pragma unroll
    for (int ci = 0; ci < 32; ci++) {
      float4 wv = wp[ci * 128];   // ci*512 floats
      acc.x += fr[ci]*wv.x; acc.y += fr[ci]*wv.y;
      acc.z += fr[ci]*wv.z; acc.w += fr[ci]*wv.w;
    }
    atomicAdd(&x1[obase + c4*4 + 0], acc.x);
    atomicAdd(&x1[obase + c4*4 + 1], acc.y);
    atomicAdd(&x1[obase + c4*4 + 2], acc.z);
    atomicAdd(&x1[obase + c4*4 + 3], acc.w);
  }
}

// ---------------- mask downsample (+ active count via ballot) ----------------
template <int DO, int HO, int WO, int DP, int HP, int WP>
__global__ __launch_bounds__(256) void k_mask(const float* __restrict__ prev,
                                              float* __restrict__ mout,
                                              float* __restrict__ nout, int nsites) {
  int s = blockIdx.x * 256 + threadIdx.x;
  bool act = false;
  if (s < nsites) {
    int b = s / (DO*HO*WO); int r = s - b*(DO*HO*WO);
    int ox = r / (HO*WO); r -= ox*(HO*WO);
    int oy = r / WO; int oz = r - oy*WO;
    int base = ((b*DP + 2*ox)*HP + 2*oy)*WP + 2*oz;
#pragma unroll
    for (int ch = 0; ch < 8; ch++) {
      int idx = base + ((ch >> 2) & 1)*HP*WP + ((ch >> 1) & 1)*WP + (ch & 1);
      act |= (prev[idx] > 0.0f);
    }
    mout[s] = act ? 1.0f : 0.0f;
  }
  unsigned long long bal = __ballot(act);
  if ((threadIdx.x & 63) == 0) atomicAdd(nout, (float)__popcll(bal));
}

// ---------------- per-channel sum / sumsq ----------------
template <int CPAD>
__global__ __launch_bounds__(256) void k_stats(const float* __restrict__ x,
                                               float* __restrict__ sum,
                                               float* __restrict__ ssum,
                                               int nsites, int rows) {
  __shared__ float rs[256], rq[256];
  int gid = blockIdx.x * 256 + threadIdx.x;
  int co = gid & (CPAD - 1);
  int row = gid / CPAD;
  float s = 0.f, q = 0.f;
  for (int site = row; site < nsites; site += rows) {
    float v = x[(size_t)site * CPAD + co];
    s += v; q += v * v;
  }
  rs[threadIdx.x] = s; rq[threadIdx.x] = q;
  __syncthreads();
  if (threadIdx.x < CPAD) {
#pragma unroll
    for (int g = 1; g < 256 / CPAD; g++) {
      s += rs[threadIdx.x + g*CPAD]; q += rq[threadIdx.x + g*CPAD];
    }
    atomicAdd(&sum[co], s); atomicAdd(&ssum[co], q);
  }
}

// ---------------- gather-GEMM conv with fused input BN+LeakyReLU+mask ----------------
// block: 32 sites x 128 couts; thread: 4 sites x 4 couts; K chunks of 64 in LDS
template <int CIN_REAL, int CIN_STRIDE, int COUT_REAL,
          int DO, int HO, int WO, int DP, int HP, int WP>
__global__ __launch_bounds__(256) void k_conv(
    const float* __restrict__ xin, const float* __restrict__ mprev,
    const float* __restrict__ Wm, const float* __restrict__ gam,
    const float* __restrict__ bet, const float* __restrict__ ssumv,
    const float* __restrict__ ssqv, const float* __restrict__ ncnt,
    float* __restrict__ xout) {
  const int K = 8 * CIN_REAL;
  __shared__ float xs[32][64];
  __shared__ float ws[64][128];
  __shared__ float sc[CIN_REAL], sh[CIN_REAL];
  __shared__ int   cbase[32][8];
  __shared__ float cmask[32][8];
  int t = threadIdx.x;
  if (t < CIN_REAL) {
    float n = fmaxf(ncnt[0], 1.0f);
    float mean = ssumv[t] / n;
    float var = ssqv[t] / n - mean * mean;
    float s = gam[t] * rsqrtf(var + EPS_);
    sc[t] = s; sh[t] = bet[t] - mean * s;
  }
  {
    int s = t >> 3, ch = t & 7;
    int g = blockIdx.x * 32 + s;
    int b = g / (DO*HO*WO); int r = g - b*(DO*HO*WO);
    int ox = r / (HO*WO); r -= ox*(HO*WO);
    int oy = r / WO; int oz = r - oy*WO;
    int ps = ((b*DP + 2*ox + ((ch >> 2) & 1))*HP + 2*oy + ((ch >> 1) & 1))*WP + 2*oz + (ch & 1);
    cbase[s][ch] = ps * CIN_STRIDE;
    cmask[s][ch] = mprev[ps];
  }
  int cq = t & 31, sq = t >> 5;
  float4 acc[4] = {{0,0,0,0},{0,0,0,0},{0,0,0,0},{0,0,0,0}};
  for (int k0 = 0; k0 < K; k0 += 64) {
    __syncthreads();
#pragma unroll
    for (int ii = 0; ii < 8; ii++) {
      int idx = t + ii*256;
      int s = idx >> 6, kk = idx & 63;
      int k = k0 + kk;
      int ch = k / CIN_REAL;
      int ci = k - ch * CIN_REAL;
      float v = xin[cbase[s][ch] + ci];
      v = v * sc[ci] + sh[ci];
      v = (v > 0.f ? v : LEAK_ * v) * cmask[s][ch];
      xs[s][kk] = v;
    }
#pragma unroll
    for (int ii = 0; ii < 32; ii++) {
      int idx = t + ii*256;
      int kk = idx >> 7, co = idx & 127;
      ws[kk][co] = (co < COUT_REAL) ? Wm[(k0 + kk)*COUT_REAL + co] : 0.0f;
    }
    __syncthreads();
#pragma unroll
    for (int kk = 0; kk < 64; kk += 4) {
      float4 w0 = *(const float4*)&ws[kk    ][cq*4];
      float4 w1v = *(const float4*)&ws[kk + 1][cq*4];
      float4 w2v = *(const float4*)&ws[kk + 2][cq*4];
      float4 w3v = *(const float4*)&ws[kk + 3][cq*4];
#pragma unroll
      for (int j = 0; j < 4; j++) {
        float4 xv = *(const float4*)&xs[sq + 8*j][kk];
        acc[j].x += xv.x*w0.x + xv.y*w1v.x + xv.z*w2v.x + xv.w*w3v.x;
        acc[j].y += xv.x*w0.y + xv.y*w1v.y + xv.z*w2v.y + xv.w*w3v.y;
        acc[j].z += xv.x*w0.z + xv.y*w1v.z + xv.z*w2v.z + xv.w*w3v.z;
        acc[j].w += xv.x*w0.w + xv.y*w1v.w + xv.z*w2v.w + xv.w*w3v.w;
      }
    }
  }
#pragma unroll
  for (int j = 0; j < 4; j++) {
    int g = blockIdx.x * 32 + sq + 8*j;
    *(float4*)&xout[(size_t)g * 128 + cq*4] = acc[j];
  }
}

// ---------------- final conv (cout=1) + sigmoid + mask ----------------
__global__ __launch_bounds__(256) void k_final(
    const float* __restrict__ x3, const float* __restrict__ m3,
    const float* __restrict__ w4, const float* __restrict__ gam,
    const float* __restrict__ bet, const float* __restrict__ ssumv,
    const float* __restrict__ ssqv, const float* __restrict__ ncnt,
    float* __restrict__ out) {
  __shared__ float sc[128], sh[128];
  __shared__ int cb[8];
  __shared__ float msk[8];
  __shared__ float red[256];
  int t = threadIdx.x;
  if (t < 128) {
    float n = fmaxf(ncnt[0], 1.0f);
    float mean = ssumv[t] / n;
    float var = ssqv[t] / n - mean * mean;
    float s = gam[t] * rsqrtf(var + EPS_);
    sc[t] = s; sh[t] = bet[t] - mean * s;
  }
  int g = blockIdx.x;
  int b = g / (D4*H4*W4); int r = g - b*(D4*H4*W4);
  int ox = r / (H4*W4); r -= ox*(H4*W4);
  int oy = r / W4; int oz = r - oy*W4;
  if (t < 8) {
    int ps = ((b*D3 + 2*ox + ((t >> 2) & 1))*H3 + 2*oy + ((t >> 1) & 1))*W3 + 2*oz + (t & 1);
    cb[t] = ps * 128;
    msk[t] = m3[ps];
  }
  __syncthreads();
  float acc = 0.f;
#pragma unroll
  for (int ii = 0; ii < 4; ii++) {
    int k = t + ii*256;
    int ch = k >> 7, ci = k & 127;
    float v = x3[cb[ch] + ci];
    v = v * sc[ci] + sh[ci];
    v = (v > 0.f ? v : LEAK_ * v) * msk[ch];
    acc += v * w4[k];
  }
  red[t] = acc;
  __syncthreads();
  if (t < 128) red[t] += red[t + 128];
  __syncthreads();
  if (t < 64) {
    float v = red[t] + red[t + 64];
#pragma unroll
    for (int off = 32; off > 0; off >>= 1) v += __shfl_down(v, off);
    if (t == 0) {
      float any = (msk[0] + msk[1] + msk[2] + msk[3] + msk[4] + msk[5] + msk[6] + msk[7]) > 0.f ? 1.f : 0.f;
      out[g] = any / (1.0f + expf(-v));
    }
  }
}

extern "C" void kernel_launch(void* const* d_in, const int* in_sizes, int n_in,
                              void* d_out, int out_size, void* d_ws, size_t ws_size,
                              hipStream_t stream) {
  (void)in_sizes; (void)n_in; (void)out_size; (void)ws_size;
  const float* feat = (const float*)d_in[0];
  const int*   crd  = (const int*)d_in[1];
  const float* w1 = (const float*)d_in[2];
  const float* g1 = (const float*)d_in[3];
  const float* b1 = (const float*)d_in[4];
  const float* w2 = (const float*)d_in[5];
  const float* g2 = (const float*)d_in[6];
  const float* b2 = (const float*)d_in[7];
  const float* w3 = (const float*)d_in[8];
  const float* g3 = (const float*)d_in[9];
  const float* b3 = (const float*)d_in[10];
  const float* w4 = (const float*)d_in[11];
  float* out = (float*)d_out;
  float* ws  = (float*)d_ws;

  float* cnt = ws + OFF_CNT;
  float* x1  = ws + OFF_X1;
  float* st  = ws + OFF_STATS;  // s1[64] q1[64] s2[128]@128 q2[128]@256 s3[128]@384 q3[128]@512 n1@640 n2@641 n3@642
  float* m1  = ws + OFF_M1;
  float* x2  = ws + OFF_X2;
  float* m2  = ws + OFF_M2;
  float* x3  = ws + OFF_X3;
  float* m3  = ws + OFF_M3;

  // zero cnt + x1 + stats (contiguous)
  hipMemsetAsync(d_ws, 0, (size_t)(OFF_STATS + 1024) * sizeof(float), stream);

  k_count<<<(PNUM + 255) / 256, 256, 0, stream>>>(crd, cnt);
  k_scatter_conv1<<<(PNUM + 255) / 256, 256, 0, stream>>>(feat, crd, cnt, w1, x1);
  k_mask<D1,H1,W1, D0,H0,W0><<<N1S / 256, 256, 0, stream>>>(cnt, m1, st + 640, N1S);
  k_stats<64><<<360, 256, 0, stream>>>(x1, st + 0, st + 64, N1S, 360 * 256 / 64);
  k_mask<D2,H2,W2, D1,H1,W1><<<N2S / 256, 256, 0, stream>>>(m1, m2, st + 641, N2S);
  k_conv<64, 64, 96, D2,H2,W2, D1,H1,W1><<<N2S / 32, 256, 0, stream>>>(
      x1, m1, w2, g1, b1, st + 0, st + 64, st + 640, x2);
  k_stats<128><<<180, 256, 0, stream>>>(x2, st + 128, st + 256, N2S, 180 * 256 / 128);
  k_mask<D3,H3,W3, D2,H2,W2><<<(N3S + 255) / 256, 256, 0, stream>>>(m2, m3, st + 642, N3S);
  k_conv<96, 128, 128, D3,H3,W3, D2,H2,W2><<<N3S / 32, 256, 0, stream>>>(
      x2, m2, w3, g2, b2, st + 128, st + 256, st + 641, x3);
  k_stats<128><<<45, 256, 0, stream>>>(x3, st + 384, st + 512, N3S, 45 * 256 / 128);
  k_final<<<N4S, 256, 0, stream>>>(x3, m3, w4, g3, b3, st + 384, st + 512, st + 642, out);
}

// Round 2
// 1146.162 us; speedup vs baseline: 1.4734x; 1.4734x over previous
//
#include <hip/hip_runtime.h>
#include <math.h>

#define PNUM 300000
#define B_ 2
#define D0 144
#define H0 64
#define W0 160
#define C0 32
#define NVOX (B_*D0*H0*W0)   // 2,949,120

#define D1 72
#define H1 32
#define W1 80
#define C1 64
#define N1S (B_*D1*H1*W1)   // 368640

#define D2 36
#define H2 16
#define W2 40
#define N2S (B_*D2*H2*W2)   // 46080

#define D3 18
#define H3 8
#define W3 20
#define N3S (B_*D3*H3*W3)   // 5760

#define D4 9
#define H4 4
#define W4 10
#define N4S (B_*D4*H4*W4)   // 720

#define EPS_ 1e-4f
#define LEAK_ 0.2f

// workspace layout (4-byte element offsets)
#define OFF_CNT    0                      // NVOX ints
#define OFF_STATS  2949120                // 1024 floats (stats + counters + gcur@643)
#define OFF_START  2950144                // NVOX ints
#define OFF_SORTED 5899264                // 300,000 ints
#define OFF_X1     6199264                // 23,592,960 floats (first NVOX overlaid by cursor)
#define OFF_M1     29792224               // 368,640
#define OFF_X2     30160864               // 5,898,240 (46080*128, couts 96..127 zero)
#define OFF_M2     36059104               // 46,080
#define OFF_X3     36105184               // 737,280
#define OFF_M3     36842464               // 5,760
// total 36,848,224 * 4B = 147.4 MB

// ---------------- densify count (int histogram) ----------------
__global__ __launch_bounds__(256) void k_count(const int* __restrict__ coords,
                                               int* __restrict__ cnt) {
  int i = blockIdx.x * 256 + threadIdx.x;
  if (i >= PNUM) return;
  int b = coords[i*4], x = coords[i*4+1], y = coords[i*4+2], z = coords[i*4+3];
  atomicAdd(&cnt[((b*D0 + x)*H0 + y)*W0 + z], 1);
}

// ---------------- slot allocation: block-scan + single ticket atomic ----------------
// start[v] = contiguous region base for voxel v's points (order across blocks is
// nondeterministic ticket order -- per-voxel contiguity is all we need).
__global__ __launch_bounds__(256) void k_alloc(const int* __restrict__ cnt,
                                               int* __restrict__ start,
                                               int* __restrict__ cursor,
                                               int* __restrict__ gcur) {
  __shared__ int wsum[4];
  __shared__ int blockBase;
  int t = threadIdx.x;
  int idx0 = blockIdx.x * 1024 + t * 4;
  int4 cv = *(const int4*)(cnt + idx0);
  int c0 = cv.x, c1 = cv.y, c2 = cv.z, c3 = cv.w;
  int tsum = c0 + c1 + c2 + c3;
  int lane = t & 63, wid = t >> 6;
  int incl = tsum;
#pragma unroll
  for (int off = 1; off < 64; off <<= 1) {
    int v = __shfl_up(incl, off);
    if (lane >= off) incl += v;
  }
  if (lane == 63) wsum[wid] = incl;
  __syncthreads();
  if (t == 0) blockBase = atomicAdd(gcur, wsum[0] + wsum[1] + wsum[2] + wsum[3]);
  __syncthreads();
  int base = blockBase;
  for (int w = 0; w < wid; w++) base += wsum[w];
  int st = base + incl - tsum;   // exclusive within block
  start[idx0 + 0] = st; cursor[idx0 + 0] = st; st += c0;
  start[idx0 + 1] = st; cursor[idx0 + 1] = st; st += c1;
  start[idx0 + 2] = st; cursor[idx0 + 2] = st; st += c2;
  start[idx0 + 3] = st; cursor[idx0 + 3] = st;
}

// ---------------- counting-sort scatter of point indices ----------------
__global__ __launch_bounds__(256) void k_scatter(const int* __restrict__ coords,
                                                 int* __restrict__ cursor,
                                                 int* __restrict__ sorted) {
  int i = blockIdx.x * 256 + threadIdx.x;
  if (i >= PNUM) return;
  int b = coords[i*4], x = coords[i*4+1], y = coords[i*4+2], z = coords[i*4+3];
  int v = ((b*D0 + x)*H0 + y)*W0 + z;
  int slot = atomicAdd(&cursor[v], 1);
  sorted[slot] = i;
}

// ---------------- gather conv1: 32 parents x 64 couts per block ----------------
// densify-average fused into LDS staging; each child voxel belongs to exactly
// one parent (stride-2, filter-2) so every feature float is read once.
__global__ __launch_bounds__(256) void k_conv1g(
    const float* __restrict__ feat, const int* __restrict__ sorted,
    const int* __restrict__ cnt, const int* __restrict__ start,
    const float* __restrict__ w1, float* __restrict__ x1) {
  __shared__ float xs[32][64];
  __shared__ float ws[64][64];
  __shared__ int cbase[32][8];
  __shared__ int ccnt[32][8];
  int t = threadIdx.x;
  {
    int s = t >> 3, ch = t & 7;
    int g = blockIdx.x * 32 + s;
    int b = g / (D1*H1*W1); int r = g - b*(D1*H1*W1);
    int ox = r / (H1*W1); r -= ox*(H1*W1);
    int oy = r / W1; int oz = r - oy*W1;
    int v = ((b*D0 + 2*ox + ((ch >> 2) & 1))*H0 + 2*oy + ((ch >> 1) & 1))*W0 + 2*oz + (ch & 1);
    cbase[s][ch] = start[v];
    ccnt[s][ch] = cnt[v];
  }
  int cq = t & 15, sq = t >> 4;
  float4 acc[2] = {{0,0,0,0},{0,0,0,0}};
  for (int k0 = 0; k0 < 256; k0 += 64) {
    __syncthreads();
#pragma unroll
    for (int ii = 0; ii < 8; ii++) {
      int idx = t + ii*256;
      int s = idx >> 6, kk = idx & 63;
      int k = k0 + kk;
      int ch = k >> 5, ci = k & 31;
      int n = ccnt[s][ch];
      float a = 0.f;
      int st = cbase[s][ch];
      for (int j = 0; j < n; j++) a += feat[(size_t)sorted[st + j] * 32 + ci];
      xs[s][kk] = (n > 0) ? a / (float)n : 0.f;
    }
#pragma unroll
    for (int ii = 0; ii < 16; ii++) {
      int idx = t + ii*256;
      int kk = idx >> 6, co = idx & 63;
      ws[kk][co] = w1[(k0 + kk)*64 + co];
    }
    __syncthreads();
#pragma unroll
    for (int kk = 0; kk < 64; kk += 4) {
      float4 w0 = *(const float4*)&ws[kk    ][cq*4];
      float4 w1v = *(const float4*)&ws[kk + 1][cq*4];
      float4 w2v = *(const float4*)&ws[kk + 2][cq*4];
      float4 w3v = *(const float4*)&ws[kk + 3][cq*4];
#pragma unroll
      for (int j = 0; j < 2; j++) {
        float4 xv = *(const float4*)&xs[sq + 16*j][kk];
        acc[j].x += xv.x*w0.x + xv.y*w1v.x + xv.z*w2v.x + xv.w*w3v.x;
        acc[j].y += xv.x*w0.y + xv.y*w1v.y + xv.z*w2v.y + xv.w*w3v.y;
        acc[j].z += xv.x*w0.z + xv.y*w1v.z + xv.z*w2v.z + xv.w*w3v.z;
        acc[j].w += xv.x*w0.w + xv.y*w1v.w + xv.z*w2v.w + xv.w*w3v.w;
      }
    }
  }
#pragma unroll
  for (int j = 0; j < 2; j++) {
    int g = blockIdx.x * 32 + sq + 16*j;
    *(float4*)&x1[(size_t)g * 64 + cq*4] = acc[j];
  }
}

// ---------------- mask downsample (+ active count via ballot) ----------------
template <typename T, int DO, int HO, int WO, int DP, int HP, int WP>
__global__ __launch_bounds__(256) void k_mask(const T* __restrict__ prev,
                                              float* __restrict__ mout,
                                              float* __restrict__ nout, int nsites) {
  int s = blockIdx.x * 256 + threadIdx.x;
  bool act = false;
  if (s < nsites) {
    int b = s / (DO*HO*WO); int r = s - b*(DO*HO*WO);
    int ox = r / (HO*WO); r -= ox*(HO*WO);
    int oy = r / WO; int oz = r - oy*WO;
    int base = ((b*DP + 2*ox)*HP + 2*oy)*WP + 2*oz;
#pragma unroll
    for (int ch = 0; ch < 8; ch++) {
      int idx = base + ((ch >> 2) & 1)*HP*WP + ((ch >> 1) & 1)*WP + (ch & 1);
      act |= (prev[idx] > (T)0);
    }
    mout[s] = act ? 1.0f : 0.0f;
  }
  unsigned long long bal = __ballot(act);
  if ((threadIdx.x & 63) == 0) atomicAdd(nout, (float)__popcll(bal));
}

// ---------------- per-channel sum / sumsq ----------------
template <int CPAD>
__global__ __launch_bounds__(256) void k_stats(const float* __restrict__ x,
                                               float* __restrict__ sum,
                                               float* __restrict__ ssum,
                                               int nsites, int rows) {
  __shared__ float rs[256], rq[256];
  int gid = blockIdx.x * 256 + threadIdx.x;
  int co = gid & (CPAD - 1);
  int row = gid / CPAD;
  float s = 0.f, q = 0.f;
  for (int site = row; site < nsites; site += rows) {
    float v = x[(size_t)site * CPAD + co];
    s += v; q += v * v;
  }
  rs[threadIdx.x] = s; rq[threadIdx.x] = q;
  __syncthreads();
  if (threadIdx.x < CPAD) {
#pragma unroll
    for (int g = 1; g < 256 / CPAD; g++) {
      s += rs[threadIdx.x + g*CPAD]; q += rq[threadIdx.x + g*CPAD];
    }
    atomicAdd(&sum[co], s); atomicAdd(&ssum[co], q);
  }
}

// ---------------- gather-GEMM conv with fused input BN+LeakyReLU+mask ----------------
template <int CIN_REAL, int CIN_STRIDE, int COUT_REAL,
          int DO, int HO, int WO, int DP, int HP, int WP>
__global__ __launch_bounds__(256) void k_conv(
    const float* __restrict__ xin, const float* __restrict__ mprev,
    const float* __restrict__ Wm, const float* __restrict__ gam,
    const float* __restrict__ bet, const float* __restrict__ ssumv,
    const float* __restrict__ ssqv, const float* __restrict__ ncnt,
    float* __restrict__ xout) {
  const int K = 8 * CIN_REAL;
  __shared__ float xs[32][64];
  __shared__ float ws[64][128];
  __shared__ float sc[CIN_REAL], sh[CIN_REAL];
  __shared__ int   cbase[32][8];
  __shared__ float cmask[32][8];
  int t = threadIdx.x;
  if (t < CIN_REAL) {
    float n = fmaxf(ncnt[0], 1.0f);
    float mean = ssumv[t] / n;
    float var = ssqv[t] / n - mean * mean;
    float s = gam[t] * rsqrtf(var + EPS_);
    sc[t] = s; sh[t] = bet[t] - mean * s;
  }
  {
    int s = t >> 3, ch = t & 7;
    int g = blockIdx.x * 32 + s;
    int b = g / (DO*HO*WO); int r = g - b*(DO*HO*WO);
    int ox = r / (HO*WO); r -= ox*(HO*WO);
    int oy = r / WO; int oz = r - oy*WO;
    int ps = ((b*DP + 2*ox + ((ch >> 2) & 1))*HP + 2*oy + ((ch >> 1) & 1))*WP + 2*oz + (ch & 1);
    cbase[s][ch] = ps * CIN_STRIDE;
    cmask[s][ch] = mprev[ps];
  }
  int cq = t & 31, sq = t >> 5;
  float4 acc[4] = {{0,0,0,0},{0,0,0,0},{0,0,0,0},{0,0,0,0}};
  for (int k0 = 0; k0 < K; k0 += 64) {
    __syncthreads();
#pragma unroll
    for (int ii = 0; ii < 8; ii++) {
      int idx = t + ii*256;
      int s = idx >> 6, kk = idx & 63;
      int k = k0 + kk;
      int ch = k / CIN_REAL;
      int ci = k - ch * CIN_REAL;
      float v = xin[cbase[s][ch] + ci];
      v = v * sc[ci] + sh[ci];
      v = (v > 0.f ? v : LEAK_ * v) * cmask[s][ch];
      xs[s][kk] = v;
    }
#pragma unroll
    for (int ii = 0; ii < 32; ii++) {
      int idx = t + ii*256;
      int kk = idx >> 7, co = idx & 127;
      ws[kk][co] = (co < COUT_REAL) ? Wm[(k0 + kk)*COUT_REAL + co] : 0.0f;
    }
    __syncthreads();
#pragma unroll
    for (int kk = 0; kk < 64; kk += 4) {
      float4 w0 = *(const float4*)&ws[kk    ][cq*4];
      float4 w1v = *(const float4*)&ws[kk + 1][cq*4];
      float4 w2v = *(const float4*)&ws[kk + 2][cq*4];
      float4 w3v = *(const float4*)&ws[kk + 3][cq*4];
#pragma unroll
      for (int j = 0; j < 4; j++) {
        float4 xv = *(const float4*)&xs[sq + 8*j][kk];
        acc[j].x += xv.x*w0.x + xv.y*w1v.x + xv.z*w2v.x + xv.w*w3v.x;
        acc[j].y += xv.x*w0.y + xv.y*w1v.y + xv.z*w2v.y + xv.w*w3v.y;
        acc[j].z += xv.x*w0.z + xv.y*w1v.z + xv.z*w2v.z + xv.w*w3v.z;
        acc[j].w += xv.x*w0.w + xv.y*w1v.w + xv.z*w2v.w + xv.w*w3v.w;
      }
    }
  }
#pragma unroll
  for (int j = 0; j < 4; j++) {
    int g = blockIdx.x * 32 + sq + 8*j;
    *(float4*)&xout[(size_t)g * 128 + cq*4] = acc[j];
  }
}

// ---------------- final conv (cout=1) + sigmoid + mask ----------------
__global__ __launch_bounds__(256) void k_final(
    const float* __restrict__ x3, const float* __restrict__ m3,
    const float* __restrict__ w4, const float* __restrict__ gam,
    const float* __restrict__ bet, const float* __restrict__ ssumv,
    const float* __restrict__ ssqv, const float* __restrict__ ncnt,
    float* __restrict__ out) {
  __shared__ float sc[128], sh[128];
  __shared__ int cb[8];
  __shared__ float msk[8];
  __shared__ float red[256];
  int t = threadIdx.x;
  if (t < 128) {
    float n = fmaxf(ncnt[0], 1.0f);
    float mean = ssumv[t] / n;
    float var = ssqv[t] / n - mean * mean;
    float s = gam[t] * rsqrtf(var + EPS_);
    sc[t] = s; sh[t] = bet[t] - mean * s;
  }
  int g = blockIdx.x;
  int b = g / (D4*H4*W4); int r = g - b*(D4*H4*W4);
  int ox = r / (H4*W4); r -= ox*(H4*W4);
  int oy = r / W4; int oz = r - oy*W4;
  if (t < 8) {
    int ps = ((b*D3 + 2*ox + ((t >> 2) & 1))*H3 + 2*oy + ((t >> 1) & 1))*W3 + 2*oz + (t & 1);
    cb[t] = ps * 128;
    msk[t] = m3[ps];
  }
  __syncthreads();
  float acc = 0.f;
#pragma unroll
  for (int ii = 0; ii < 4; ii++) {
    int k = t + ii*256;
    int ch = k >> 7, ci = k & 127;
    float v = x3[cb[ch] + ci];
    v = v * sc[ci] + sh[ci];
    v = (v > 0.f ? v : LEAK_ * v) * msk[ch];
    acc += v * w4[k];
  }
  red[t] = acc;
  __syncthreads();
  if (t < 128) red[t] += red[t + 128];
  __syncthreads();
  if (t < 64) {
    float v = red[t] + red[t + 64];
#pragma unroll
    for (int off = 32; off > 0; off >>= 1) v += __shfl_down(v, off);
    if (t == 0) {
      float any = (msk[0] + msk[1] + msk[2] + msk[3] + msk[4] + msk[5] + msk[6] + msk[7]) > 0.f ? 1.f : 0.f;
      out[g] = any / (1.0f + expf(-v));
    }
  }
}

extern "C" void kernel_launch(void* const* d_in, const int* in_sizes, int n_in,
                              void* d_out, int out_size, void* d_ws, size_t ws_size,
                              hipStream_t stream) {
  (void)in_sizes; (void)n_in; (void)out_size; (void)ws_size;
  const float* feat = (const float*)d_in[0];
  const int*   crd  = (const int*)d_in[1];
  const float* w1 = (const float*)d_in[2];
  const float* g1 = (const float*)d_in[3];
  const float* b1 = (const float*)d_in[4];
  const float* w2 = (const float*)d_in[5];
  const float* g2 = (const float*)d_in[6];
  const float* b2 = (const float*)d_in[7];
  const float* w3 = (const float*)d_in[8];
  const float* g3 = (const float*)d_in[9];
  const float* b3 = (const float*)d_in[10];
  const float* w4 = (const float*)d_in[11];
  float* out = (float*)d_out;
  float* ws  = (float*)d_ws;

  int*   cnt    = (int*)(ws + OFF_CNT);
  float* st     = ws + OFF_STATS;   // s1@0 q1@64 s2@128 q2@256 s3@384 q3@512 n1@640 n2@641 n3@642 gcur@643
  int*   start  = (int*)(ws + OFF_START);
  int*   sorted = (int*)(ws + OFF_SORTED);
  float* x1     = ws + OFF_X1;
  int*   cursor = (int*)(ws + OFF_X1);    // overlays x1 (dead before conv1g writes)
  float* m1     = ws + OFF_M1;
  float* x2     = ws + OFF_X2;
  float* m2     = ws + OFF_M2;
  float* x3     = ws + OFF_X3;
  float* m3     = ws + OFF_M3;

  // zero cnt + stats (contiguous prefix)
  hipMemsetAsync(d_ws, 0, (size_t)(OFF_STATS + 1024) * sizeof(float), stream);

  k_count<<<(PNUM + 255) / 256, 256, 0, stream>>>(crd, cnt);
  k_alloc<<<NVOX / 1024, 256, 0, stream>>>(cnt, start, cursor, (int*)(st + 643));
  k_scatter<<<(PNUM + 255) / 256, 256, 0, stream>>>(crd, cursor, sorted);
  k_conv1g<<<N1S / 32, 256, 0, stream>>>(feat, sorted, cnt, start, w1, x1);
  k_mask<int, D1,H1,W1, D0,H0,W0><<<N1S / 256, 256, 0, stream>>>(cnt, m1, st + 640, N1S);
  k_stats<64><<<360, 256, 0, stream>>>(x1, st + 0, st + 64, N1S, 360 * 256 / 64);
  k_mask<float, D2,H2,W2, D1,H1,W1><<<N2S / 256, 256, 0, stream>>>(m1, m2, st + 641, N2S);
  k_conv<64, 64, 96, D2,H2,W2, D1,H1,W1><<<N2S / 32, 256, 0, stream>>>(
      x1, m1, w2, g1, b1, st + 0, st + 64, st + 640, x2);
  k_stats<128><<<180, 256, 0, stream>>>(x2, st + 128, st + 256, N2S, 180 * 256 / 128);
  k_mask<float, D3,H3,W3, D2,H2,W2><<<(N3S + 255) / 256, 256, 0, stream>>>(m2, m3, st + 642, N3S);
  k_conv<96, 128, 128, D3,H3,W3, D2,H2,W2><<<N3S / 32, 256, 0, stream>>>(
      x2, m2, w3, g2, b2, st + 128, st + 256, st + 641, x3);
  k_stats<128><<<45, 256, 0, stream>>>(x3, st + 384, st + 512, N3S, 45 * 256 / 128);
  k_final<<<N4S, 256, 0, stream>>>(x3, m3, w4, g3, b3, st + 384, st + 512, st + 642, out);
}